// Round 4
// baseline (1829.073 us; speedup 1.0000x reference)
//
#include <hip/hip_runtime.h>
#include <hip/hip_bf16.h>
#include <cstdint>
#include <cstddef>

// Problem constants (match reference)
#define BB      4
#define CC      384
#define HH      128
#define WW2     128
#define NN      16384      // H*W
#define NHEADS  8
#define HD      48         // CC / NHEADS
#define PROJK   768        // 2*CC

// ---------------------------------------------------------------------------
// GEMM + folded BatchNorm epilogue.
// out[b][o][n] = (sum_c W[o][c]*in[b][c][n] + bias[o]) * s[o] + (beta - mean*s)[o]
//   with s = g * rsqrt(var + eps)
// Tile: BM=128 (o) x BN=128 (n) x BK=16, 256 threads, 8x8 micro-tile.
// b comes from blockIdx.z; launching with gridDim.z==1 and batch-offset
// pointers is equivalent to the b-th slice.
// ---------------------------------------------------------------------------
__global__ __launch_bounds__(256)
void gemm_bn_kernel(const float* __restrict__ in, const float* __restrict__ Wm,
                    const float* __restrict__ bias, const float* __restrict__ g,
                    const float* __restrict__ beta, const float* __restrict__ mean,
                    const float* __restrict__ var, float* __restrict__ out) {
    __shared__ float Ws[16][132];   // [k][o], padded stride 132
    __shared__ float Xs[16][132];   // [k][n]

    const int t  = threadIdx.x;
    const int b  = blockIdx.z;
    const int o0 = blockIdx.y * 128;
    const int n0 = blockIdx.x * 128;
    const float* inb = in + (size_t)b * CC * NN;

    const int tx = t & 15;          // n-group: cols tx*8 .. tx*8+7
    const int ty = t >> 4;          // o-group: rows ty*8 .. ty*8+7

    // staging thread mapping
    const int wr = t >> 1;          // 0..127  (W tile row)
    const int wh = (t & 1) * 8;     // 0 or 8  (W tile k-half)
    const int xr = t >> 4;          // 0..15   (X tile row = k)
    const int xc = (t & 15) * 8;    // X tile col

    float acc[8][8];
    #pragma unroll
    for (int i = 0; i < 8; ++i)
        #pragma unroll
        for (int j = 0; j < 8; ++j) acc[i][j] = 0.f;

    for (int k0 = 0; k0 < CC; k0 += 16) {
        const float4 w0 = *(const float4*)&Wm[(size_t)(o0 + wr) * CC + k0 + wh];
        const float4 w1 = *(const float4*)&Wm[(size_t)(o0 + wr) * CC + k0 + wh + 4];
        const float4 x0 = *(const float4*)&inb[(size_t)(k0 + xr) * NN + n0 + xc];
        const float4 x1 = *(const float4*)&inb[(size_t)(k0 + xr) * NN + n0 + xc + 4];

        __syncthreads();   // previous iteration's LDS reads done
        Ws[wh + 0][wr] = w0.x; Ws[wh + 1][wr] = w0.y;
        Ws[wh + 2][wr] = w0.z; Ws[wh + 3][wr] = w0.w;
        Ws[wh + 4][wr] = w1.x; Ws[wh + 5][wr] = w1.y;
        Ws[wh + 6][wr] = w1.z; Ws[wh + 7][wr] = w1.w;
        *(float4*)&Xs[xr][xc]     = x0;
        *(float4*)&Xs[xr][xc + 4] = x1;
        __syncthreads();

        #pragma unroll
        for (int kk = 0; kk < 16; ++kk) {
            float wv[8], xv[8];
            *(float4*)&wv[0] = *(const float4*)&Ws[kk][ty * 8];
            *(float4*)&wv[4] = *(const float4*)&Ws[kk][ty * 8 + 4];
            *(float4*)&xv[0] = *(const float4*)&Xs[kk][tx * 8];
            *(float4*)&xv[4] = *(const float4*)&Xs[kk][tx * 8 + 4];
            #pragma unroll
            for (int i = 0; i < 8; ++i)
                #pragma unroll
                for (int j = 0; j < 8; ++j)
                    acc[i][j] = fmaf(wv[i], xv[j], acc[i][j]);
        }
    }

    #pragma unroll
    for (int i = 0; i < 8; ++i) {
        const int oo = o0 + ty * 8 + i;
        const float s   = g[oo] * rsqrtf(var[oo] + 1e-5f);
        const float gam = bias[oo] * s + beta[oo] - mean[oo] * s;
        float4 r0, r1;
        r0.x = acc[i][0] * s + gam; r0.y = acc[i][1] * s + gam;
        r0.z = acc[i][2] * s + gam; r0.w = acc[i][3] * s + gam;
        r1.x = acc[i][4] * s + gam; r1.y = acc[i][5] * s + gam;
        r1.z = acc[i][6] * s + gam; r1.w = acc[i][7] * s + gam;
        float* op = out + ((size_t)b * CC + oo) * NN + n0 + tx * 8;
        *(float4*)op       = r0;
        *(float4*)(op + 4) = r1;
    }
}

// ---------------------------------------------------------------------------
// Final GEMM: out[b][o][n] = sum_{d<384} Wf[b][o][d]*vx[b][d][n]
//                          + sum_{d<384} Wf[b][o][384+d]*vp[b][d][n]
// ---------------------------------------------------------------------------
__global__ __launch_bounds__(256)
void gemm_final_kernel(const float* __restrict__ Wf, const float* __restrict__ vx,
                       const float* __restrict__ vp, float* __restrict__ out) {
    __shared__ float Ws[16][132];
    __shared__ float Xs[16][132];

    const int t  = threadIdx.x;
    const int b  = blockIdx.z;
    const int o0 = blockIdx.y * 128;
    const int n0 = blockIdx.x * 128;
    const float* A = Wf + (size_t)b * CC * PROJK;

    const int tx = t & 15;
    const int ty = t >> 4;
    const int wr = t >> 1;
    const int wh = (t & 1) * 8;
    const int xr = t >> 4;
    const int xc = (t & 15) * 8;

    float acc[8][8];
    #pragma unroll
    for (int i = 0; i < 8; ++i)
        #pragma unroll
        for (int j = 0; j < 8; ++j) acc[i][j] = 0.f;

    for (int k0 = 0; k0 < PROJK; k0 += 16) {
        const float* src = (k0 < CC) ? vx : vp;
        const int    kc  = (k0 < CC) ? k0 : (k0 - CC);

        const float4 w0 = *(const float4*)&A[(size_t)(o0 + wr) * PROJK + k0 + wh];
        const float4 w1 = *(const float4*)&A[(size_t)(o0 + wr) * PROJK + k0 + wh + 4];
        const float4 x0 = *(const float4*)&src[((size_t)b * CC + kc + xr) * NN + n0 + xc];
        const float4 x1 = *(const float4*)&src[((size_t)b * CC + kc + xr) * NN + n0 + xc + 4];

        __syncthreads();
        Ws[wh + 0][wr] = w0.x; Ws[wh + 1][wr] = w0.y;
        Ws[wh + 2][wr] = w0.z; Ws[wh + 3][wr] = w0.w;
        Ws[wh + 4][wr] = w1.x; Ws[wh + 5][wr] = w1.y;
        Ws[wh + 6][wr] = w1.z; Ws[wh + 7][wr] = w1.w;
        *(float4*)&Xs[xr][xc]     = x0;
        *(float4*)&Xs[xr][xc + 4] = x1;
        __syncthreads();

        #pragma unroll
        for (int kk = 0; kk < 16; ++kk) {
            float wv[8], xv[8];
            *(float4*)&wv[0] = *(const float4*)&Ws[kk][ty * 8];
            *(float4*)&wv[4] = *(const float4*)&Ws[kk][ty * 8 + 4];
            *(float4*)&xv[0] = *(const float4*)&Xs[kk][tx * 8];
            *(float4*)&xv[4] = *(const float4*)&Xs[kk][tx * 8 + 4];
            #pragma unroll
            for (int i = 0; i < 8; ++i)
                #pragma unroll
                for (int j = 0; j < 8; ++j)
                    acc[i][j] = fmaf(wv[i], xv[j], acc[i][j]);
        }
    }

    #pragma unroll
    for (int i = 0; i < 8; ++i) {
        const int oo = o0 + ty * 8 + i;
        float4 r0, r1;
        r0.x = acc[i][0]; r0.y = acc[i][1]; r0.z = acc[i][2]; r0.w = acc[i][3];
        r1.x = acc[i][4]; r1.y = acc[i][5]; r1.z = acc[i][6]; r1.w = acc[i][7];
        float* op = out + ((size_t)b * CC + oo) * NN + n0 + tx * 8;
        *(float4*)op       = r0;
        *(float4*)(op + 4) = r1;
    }
}

// ---------------------------------------------------------------------------
// Depthwise 3x3, SAME padding. Each thread computes 4 consecutive x pixels.
// grid: (H/8, C, B or 1), block 256 (8 rows x 32 col-groups).
// ---------------------------------------------------------------------------
__global__ __launch_bounds__(256)
void dwconv_kernel(const float* __restrict__ in, const float* __restrict__ w,
                   float* __restrict__ out) {
    const int t  = threadIdx.x;
    const int c  = blockIdx.y;
    const int b  = blockIdx.z;
    const int y  = blockIdx.x * 8 + (t >> 5);
    const int x0 = (t & 31) * 4;
    const size_t base = ((size_t)b * CC + c) * NN;
    const float* wc = w + c * 9;

    float4 acc = {0.f, 0.f, 0.f, 0.f};
    #pragma unroll
    for (int dy = -1; dy <= 1; ++dy) {
        const int yy = y + dy;
        if (yy < 0 || yy >= HH) continue;
        const float* rp = in + base + (size_t)yy * WW2 + x0;
        const float4 v = *(const float4*)rp;
        const float l = (x0 > 0)        ? rp[-1] : 0.f;
        const float r = (x0 + 4 < WW2)  ? rp[4]  : 0.f;
        const float a0 = wc[(dy + 1) * 3 + 0];
        const float a1 = wc[(dy + 1) * 3 + 1];
        const float a2 = wc[(dy + 1) * 3 + 2];
        acc.x += a0 * l   + a1 * v.x + a2 * v.y;
        acc.y += a0 * v.x + a1 * v.y + a2 * v.z;
        acc.z += a0 * v.y + a1 * v.z + a2 * v.w;
        acc.w += a0 * v.z + a1 * v.w + a2 * r;
    }
    *(float4*)(out + base + (size_t)y * WW2 + x0) = acc;
}

// ---------------------------------------------------------------------------
// Attention logits (partial, split-K over n): attn[b,h,c,d] += sum_n q*k
// grid: (16 n-chunks, 8 heads, B or 1), block 256, 3x3 acc per thread.
// ---------------------------------------------------------------------------
__global__ __launch_bounds__(256)
void attn_partial_kernel(const float* __restrict__ q, const float* __restrict__ k,
                         float* __restrict__ attn) {
    __shared__ float Qs[48][68];
    __shared__ float Ks[48][68];

    const int t  = threadIdx.x;
    const int h  = blockIdx.y;
    const int b  = blockIdx.z;
    const int n0 = blockIdx.x * 1024;
    const size_t base = ((size_t)b * CC + h * HD) * NN;

    const int c0 = (t >> 4) * 3;    // 0..45
    const int d0 = (t & 15) * 3;    // 0..45

    float acc[3][3];
    #pragma unroll
    for (int i = 0; i < 3; ++i)
        #pragma unroll
        for (int j = 0; j < 3; ++j) acc[i][j] = 0.f;

    for (int nb = 0; nb < 1024; nb += 64) {
        __syncthreads();
        #pragma unroll
        for (int i = 0; i < 3; ++i) {
            const int idx = i * 256 + t;       // 0..767
            const int r   = idx >> 4;          // 0..47
            const int c4  = (idx & 15) * 4;    // 0..60
            *(float4*)&Qs[r][c4] = *(const float4*)&q[base + (size_t)r * NN + n0 + nb + c4];
            *(float4*)&Ks[r][c4] = *(const float4*)&k[base + (size_t)r * NN + n0 + nb + c4];
        }
        __syncthreads();
        #pragma unroll 4
        for (int kk = 0; kk < 64; ++kk) {
            float qv[3], kv[3];
            qv[0] = Qs[c0][kk]; qv[1] = Qs[c0 + 1][kk]; qv[2] = Qs[c0 + 2][kk];
            kv[0] = Ks[d0][kk]; kv[1] = Ks[d0 + 1][kk]; kv[2] = Ks[d0 + 2][kk];
            #pragma unroll
            for (int i = 0; i < 3; ++i)
                #pragma unroll
                for (int j = 0; j < 3; ++j)
                    acc[i][j] = fmaf(qv[i], kv[j], acc[i][j]);
        }
    }

    float* ap = attn + ((size_t)b * NHEADS + h) * HD * HD;
    #pragma unroll
    for (int i = 0; i < 3; ++i)
        #pragma unroll
        for (int j = 0; j < 3; ++j)
            atomicAdd(&ap[(c0 + i) * HD + d0 + j], acc[i][j]);
}

// ---------------------------------------------------------------------------
// Row softmax over d (48), with temperature scale. One block per (b,h) —
// grid.x = (#batches in this launch) * NHEADS, h = blockIdx.x & 7.
// ---------------------------------------------------------------------------
__global__ void softmax_kernel(float* __restrict__ attn, const float* __restrict__ temp) {
    const int bh = blockIdx.x;
    const int h  = bh & 7;
    const int t  = threadIdx.x;        // 64
    if (t >= HD) return;
    float* row = attn + ((size_t)bh * HD + t) * HD;
    const float tp = temp[h];

    float v[HD];
    float m = -1e30f;
    #pragma unroll
    for (int d = 0; d < HD; ++d) { v[d] = row[d] * tp; m = fmaxf(m, v[d]); }
    float s = 0.f;
    #pragma unroll
    for (int d = 0; d < HD; ++d) { v[d] = expf(v[d] - m); s += v[d]; }
    const float inv = 1.f / s;
    #pragma unroll
    for (int d = 0; d < HD; ++d) row[d] = v[d] * inv;
}

// ---------------------------------------------------------------------------
// Fold softmaxed attention into projection weights:
// Wf[b][o][s*384 + hd*48 + d] = sum_c proj[o][s*384 + hd*48 + c] * attn[b,hd,c,d]
// grid: (384 o, B or 1), block 256 (3 outputs each).
// ---------------------------------------------------------------------------
__global__ __launch_bounds__(256)
void fold_kernel(const float* __restrict__ attn, const float* __restrict__ proj,
                 float* __restrict__ Wf) {
    const int o = blockIdx.x;
    const int b = blockIdx.y;
    const int t = threadIdx.x;
    #pragma unroll
    for (int i = 0; i < 3; ++i) {
        const int j  = i * 256 + t;     // 0..767
        const int s  = j / CC;          // 0 (vx) or 1 (vp)
        const int r  = j - s * CC;
        const int hd = r / HD;
        const int d  = r - hd * HD;
        const float* pw = proj + (size_t)o * PROJK + s * CC + hd * HD;
        const float* am = attn + ((size_t)b * NHEADS + hd) * HD * HD + d;
        float sum = 0.f;
        #pragma unroll 8
        for (int c = 0; c < HD; ++c) sum = fmaf(pw[c], am[c * HD], sum);
        Wf[((size_t)b * CC + o) * PROJK + j] = sum;
    }
}

// ---------------------------------------------------------------------------
// Adaptive workspace layout. Path A (whole-batch) needs ~206 MB; Path B
// (per-batch loop) needs ~52 MB. ws_size is constant across calls, so the
// branch is graph-capture-safe (same work every call).
// ---------------------------------------------------------------------------
extern "C" void kernel_launch(void* const* d_in, const int* in_sizes, int n_in,
                              void* d_out, int out_size, void* d_ws, size_t ws_size,
                              hipStream_t stream) {
    (void)in_sizes; (void)n_in; (void)out_size;

    const float* x      = (const float*)d_in[0];
    const float* p      = (const float*)d_in[1];
    const float* temp   = (const float*)d_in[2];
    const float* k_w    = (const float*)d_in[3];
    const float* k_b    = (const float*)d_in[4];
    const float* v_w    = (const float*)d_in[5];
    const float* v_b    = (const float*)d_in[6];
    const float* pq_w   = (const float*)d_in[7];
    const float* pq_b   = (const float*)d_in[8];
    const float* pv_w   = (const float*)d_in[9];
    const float* pv_b   = (const float*)d_in[10];
    const float* k_g    = (const float*)d_in[11];
    const float* k_beta = (const float*)d_in[12];
    const float* k_m    = (const float*)d_in[13];
    const float* k_var  = (const float*)d_in[14];
    const float* v_g    = (const float*)d_in[15];
    const float* v_beta = (const float*)d_in[16];
    const float* v_m    = (const float*)d_in[17];
    const float* v_var  = (const float*)d_in[18];
    const float* pq_g   = (const float*)d_in[19];
    const float* pq_beta= (const float*)d_in[20];
    const float* pq_m   = (const float*)d_in[21];
    const float* pq_var = (const float*)d_in[22];
    const float* pv_g   = (const float*)d_in[23];
    const float* pv_beta= (const float*)d_in[24];
    const float* pv_m   = (const float*)d_in[25];
    const float* pv_var = (const float*)d_in[26];
    const float* dwk_w  = (const float*)d_in[27];
    const float* dwv_w  = (const float*)d_in[28];
    const float* dwq_w  = (const float*)d_in[29];
    const float* dwpv_w = (const float*)d_in[30];
    const float* proj_w = (const float*)d_in[31];

    float* ws   = (float*)d_ws;
    float* outf = (float*)d_out;

    const size_t TS   = (size_t)BB * CC * NN;            // full tensor, floats
    const size_t TSB  = (size_t)CC * NN;                 // per-batch tensor, floats
    const size_t ATT  = (size_t)BB * NHEADS * HD * HD;   // attn, floats
    const size_t ATTB = (size_t)NHEADS * HD * HD;
    const size_t WFS  = (size_t)BB * CC * PROJK;         // folded proj, floats
    const size_t WFB  = (size_t)CC * PROJK;

    const size_t needA = (2 * TS + ATT + WFS) * sizeof(float);   // ~206.3 MB
    // Path B needs (2*TSB + ATTB + WFB)*4 ~ 51.6 MB

    if (ws_size >= needA) {
        // ----- Path A: whole-batch schedule -----
        float* buf0 = ws;                 // k, later vp
        float* buf1 = ws + TS;            // q, later vx
        float* attn = ws + 2 * TS;
        float* Wf   = attn + ATT;

        hipMemsetAsync(attn, 0, ATT * sizeof(float), stream);

        const dim3 gg(NN / 128, CC / 128, BB);
        const dim3 gd(HH / 8, CC, BB);

        gemm_bn_kernel<<<gg, 256, 0, stream>>>(x, k_w, k_b, k_g, k_beta, k_m, k_var, outf);
        dwconv_kernel<<<gd, 256, 0, stream>>>(outf, dwk_w, buf0);
        gemm_bn_kernel<<<gg, 256, 0, stream>>>(p, pq_w, pq_b, pq_g, pq_beta, pq_m, pq_var, outf);
        dwconv_kernel<<<gd, 256, 0, stream>>>(outf, dwq_w, buf1);

        attn_partial_kernel<<<dim3(16, NHEADS, BB), 256, 0, stream>>>(buf1, buf0, attn);
        softmax_kernel<<<BB * NHEADS, 64, 0, stream>>>(attn, temp);
        fold_kernel<<<dim3(CC, BB), 256, 0, stream>>>(attn, proj_w, Wf);

        gemm_bn_kernel<<<gg, 256, 0, stream>>>(x, v_w, v_b, v_g, v_beta, v_m, v_var, outf);
        dwconv_kernel<<<gd, 256, 0, stream>>>(outf, dwv_w, buf1);
        gemm_bn_kernel<<<gg, 256, 0, stream>>>(p, pv_w, pv_b, pv_g, pv_beta, pv_m, pv_var, outf);
        dwconv_kernel<<<gd, 256, 0, stream>>>(outf, dwpv_w, buf0);

        gemm_final_kernel<<<dim3(NN / 128, CC / 128, BB), 256, 0, stream>>>(Wf, buf1, buf0, outf);
    } else {
        // ----- Path B: per-batch loop, ~52 MB workspace -----
        float* buf0 = ws;                 // per-batch k, later vp
        float* buf1 = ws + TSB;           // per-batch q, later vx
        float* attn = ws + 2 * TSB;       // per-batch attn
        float* Wf   = attn + ATTB;        // per-batch folded proj

        const dim3 gg(NN / 128, CC / 128, 1);
        const dim3 gd(HH / 8, CC, 1);

        for (int b = 0; b < BB; ++b) {
            const float* xb = x + (size_t)b * TSB;
            const float* pb = p + (size_t)b * TSB;
            float* outb = outf + (size_t)b * TSB;

            hipMemsetAsync(attn, 0, ATTB * sizeof(float), stream);

            gemm_bn_kernel<<<gg, 256, 0, stream>>>(xb, k_w, k_b, k_g, k_beta, k_m, k_var, outb);
            dwconv_kernel<<<gd, 256, 0, stream>>>(outb, dwk_w, buf0);
            gemm_bn_kernel<<<gg, 256, 0, stream>>>(pb, pq_w, pq_b, pq_g, pq_beta, pq_m, pq_var, outb);
            dwconv_kernel<<<gd, 256, 0, stream>>>(outb, dwq_w, buf1);

            attn_partial_kernel<<<dim3(16, NHEADS, 1), 256, 0, stream>>>(buf1, buf0, attn);
            softmax_kernel<<<NHEADS, 64, 0, stream>>>(attn, temp);
            fold_kernel<<<dim3(CC, 1), 256, 0, stream>>>(attn, proj_w, Wf);

            gemm_bn_kernel<<<gg, 256, 0, stream>>>(xb, v_w, v_b, v_g, v_beta, v_m, v_var, outb);
            dwconv_kernel<<<gd, 256, 0, stream>>>(outb, dwv_w, buf1);
            gemm_bn_kernel<<<gg, 256, 0, stream>>>(pb, pv_w, pv_b, pv_g, pv_beta, pv_m, pv_var, outb);
            dwconv_kernel<<<gd, 256, 0, stream>>>(outb, dwpv_w, buf0);

            gemm_final_kernel<<<dim3(NN / 128, CC / 128, 1), 256, 0, stream>>>(Wf, buf1, buf0, outb);
        }
    }
}